// Round 1
// baseline (390.310 us; speedup 1.0000x reference)
//
#include <hip/hip_runtime.h>

typedef unsigned short ushort_t;
typedef unsigned int uint_t;
typedef __attribute__((ext_vector_type(8))) short bf8_t;   // 8 x bf16 (4 VGPRs)
typedef __attribute__((ext_vector_type(4))) float f4_t;    // MFMA acc
typedef __attribute__((ext_vector_type(4))) unsigned int u4_t;

#define NPTS 200000
#define MSUB 50000
#define KNBR 32
#define PK 15
#define INDIM 128
#define OUTDIM 256
#define HID 64
#define QD 960  // PK*HID

__device__ __forceinline__ ushort_t f2bf(float f) {
  uint_t u = __float_as_uint(f);
  u = (u + 0x7fffu + ((u >> 16) & 1u)) >> 16;  // RNE
  return (ushort_t)u;
}
__device__ __forceinline__ float bf2f(ushort_t h) {
  return __uint_as_float(((uint_t)h) << 16);
}
__device__ __forceinline__ float lrelu(float x) { return fmaxf(x, 0.1f * x); }
__device__ __forceinline__ f4_t zero4() { f4_t z = {0.f, 0.f, 0.f, 0.f}; return z; }

// ---------------- prep: features f32 -> bf16 ----------------
__global__ __launch_bounds__(256) void prep_feat_kernel(const float* __restrict__ f,
                                                        ushort_t* __restrict__ o) {
  const int i = blockIdx.x * 256 + threadIdx.x;  // one float4 (grid sized exactly)
  const float4 v = ((const float4*)f)[i];
  uint2 p;
  p.x = (uint_t)f2bf(v.x) | ((uint_t)f2bf(v.y) << 16);
  p.y = (uint_t)f2bf(v.z) | ((uint_t)f2bf(v.w) << 16);
  ((uint2*)o)[i] = p;
}

// ---------------- prep: weight transposes to bf16 ----------------
__global__ void prep_w_kernel(const float* __restrict__ W1, const float* __restrict__ W2,
                              const float* __restrict__ Ws, const float* __restrict__ kpw,
                              ushort_t* __restrict__ W1t, ushort_t* __restrict__ W2t,
                              ushort_t* __restrict__ Wst, ushort_t* __restrict__ kpwT) {
  const int base = blockIdx.x * blockDim.x + threadIdx.x;
  const int stride = gridDim.x * blockDim.x;
  for (int t = base; t < HID * INDIM; t += stride) {      // W1t[c][k] = W1[k][c]
    int c = t & 63, k = t >> 6;
    W1t[c * INDIM + k] = f2bf(W1[k * HID + c]);
  }
  for (int t = base; t < OUTDIM * HID; t += stride) {     // W2t[c][k]
    int c = t & 255, k = t >> 8;
    W2t[c * HID + k] = f2bf(W2[k * OUTDIM + c]);
  }
  for (int t = base; t < OUTDIM * INDIM; t += stride) {   // Wst[c][k]
    int c = t & 255, k = t >> 8;
    Wst[c * INDIM + k] = f2bf(Ws[k * OUTDIM + c]);
  }
  for (int t = base; t < HID * QD; t += stride) {         // kpwT[d][q] = kpw[q][d]
    int d = t & 63, q = t >> 6;
    kpwT[d * QD + q] = f2bf(kpw[q * HID + d]);
  }
}

// ---------------- conv1: [N,128] @ [128,64] (bf16 MFMA) + stats ----------------
__global__ __launch_bounds__(256) void conv1_kernel(const ushort_t* __restrict__ feat16,
                                                    const ushort_t* __restrict__ W1t,
                                                    ushort_t* __restrict__ x1,
                                                    float* __restrict__ ssum,
                                                    float* __restrict__ ssq) {
  const int tid = threadIdx.x, wid = tid >> 6, lane = tid & 63;
  const int g = lane >> 4, r16 = lane & 15;
  const int rowbase = blockIdx.x * 128 + wid * 32;
  f4_t acc[2][4];
#pragma unroll
  for (int mi = 0; mi < 2; ++mi)
#pragma unroll
    for (int ni = 0; ni < 4; ++ni) acc[mi][ni] = zero4();
#pragma unroll
  for (int kc = 0; kc < 4; ++kc) {
    const int k0 = kc * 32 + g * 8;
    bf8_t a[2], b[4];
#pragma unroll
    for (int mi = 0; mi < 2; ++mi) {
      int row = rowbase + mi * 16 + r16;
      if (row >= NPTS) row = 0;
      a[mi] = *(const bf8_t*)(feat16 + (long)row * INDIM + k0);
    }
#pragma unroll
    for (int ni = 0; ni < 4; ++ni)
      b[ni] = *(const bf8_t*)(W1t + (r16 + ni * 16) * INDIM + k0);
#pragma unroll
    for (int mi = 0; mi < 2; ++mi)
#pragma unroll
      for (int ni = 0; ni < 4; ++ni)
        acc[mi][ni] = __builtin_amdgcn_mfma_f32_16x16x32_bf16(a[mi], b[ni], acc[mi][ni], 0, 0, 0);
  }
  __shared__ float red[2][64];
  if (tid < 64) { red[0][tid] = 0.f; red[1][tid] = 0.f; }
  __syncthreads();
  float cs[4] = {0.f, 0.f, 0.f, 0.f}, cq[4] = {0.f, 0.f, 0.f, 0.f};
#pragma unroll
  for (int mi = 0; mi < 2; ++mi)
#pragma unroll
    for (int rr = 0; rr < 4; ++rr) {
      const int row = rowbase + mi * 16 + g * 4 + rr;
      if (row < NPTS) {
#pragma unroll
        for (int ni = 0; ni < 4; ++ni) {
          const float v = acc[mi][ni][rr];
          cs[ni] += v;
          cq[ni] += v * v;
          x1[(long)row * HID + r16 + ni * 16] = f2bf(v);
        }
      }
    }
#pragma unroll
  for (int ni = 0; ni < 4; ++ni) {
    atomicAdd(&red[0][r16 + ni * 16], cs[ni]);
    atomicAdd(&red[1][r16 + ni * 16], cq[ni]);
  }
  __syncthreads();
  if (tid < 64) {
    atomicAdd(&ssum[tid], red[0][tid]);
    atomicAdd(&ssq[tid], red[1][tid]);
  }
}

// ---------------- BN finalize ----------------
__global__ void fin1_kernel(float* st, const float* __restrict__ g1, const float* __restrict__ be1) {
  const int c = threadIdx.x;  // 64
  const float mu = st[c] / (float)NPTS;
  const float var = st[64 + c] / (float)NPTS - mu * mu;
  const float a = g1[c] * rsqrtf(var + 1e-5f);
  st[128 + c] = a;
  st[192 + c] = be1[c] - mu * a;
}
__global__ void fin23_kernel(float* st, const float* __restrict__ g2, const float* __restrict__ be2,
                             const float* __restrict__ gs, const float* __restrict__ bes) {
  const int c = threadIdx.x;  // 256
  {
    const float mu = st[256 + c] / (float)MSUB;
    const float var = st[512 + c] / (float)MSUB - mu * mu;
    const float a = g2[c] * rsqrtf(var + 1e-5f);
    st[768 + c] = a;
    st[1024 + c] = be2[c] - mu * a;
  }
  {
    const float mu = st[1280 + c] / (float)MSUB;
    const float var = st[1536 + c] / (float)MSUB - mu * mu;
    const float a = gs[c] * rsqrtf(var + 1e-5f);
    st[1792 + c] = a;
    st[2048 + c] = bes[c] - mu * a;
  }
}

// ---------------- gather: per-m agg (MFMA) + shortcut max ----------------
// one wave per m; agg^T[p][c] = w^T[16x32] @ f[32x64] via 4x mfma_16x16x32
__global__ __launch_bounds__(256) void gather_kernel(
    const float* __restrict__ points, const float* __restrict__ subp,
    const int* __restrict__ pools, const float* __restrict__ kp,
    const ushort_t* __restrict__ x1, const ushort_t* __restrict__ feat16,
    const float* __restrict__ a1, const float* __restrict__ s1,
    ushort_t* __restrict__ agg, ushort_t* __restrict__ scmax) {
  const int tid = threadIdx.x, wid = tid >> 6, lane = tid & 63;
  const int g = lane >> 4, r16 = lane & 15, l31 = lane & 31;
  const int m = blockIdx.x * 4 + wid;
  __shared__ __align__(16) uint_t ft2[4][32][36];  // [wave][c2][k] u32 = 2 bf16
  __shared__ float pts[4][32][3];
  __shared__ int idxs[4][32];
  __shared__ float kpp[16][3];
  __shared__ float a1s[64], s1s[64];
  if (tid < 48) kpp[tid / 3][tid % 3] = (tid < 45) ? kp[tid] : 0.f;
  if (tid < 64) { a1s[tid] = a1[tid]; s1s[tid] = s1[tid]; }
  if (lane < 32) idxs[wid][lane] = pools[m * KNBR + lane];
  __syncthreads();
  if (lane < 32) {
    const int n = idxs[wid][lane];
    pts[wid][lane][0] = points[n * 3 + 0];
    pts[wid][lane][1] = points[n * 3 + 1];
    pts[wid][lane][2] = points[n * 3 + 2];
  }
  const float sx = subp[m * 3 + 0], sy = subp[m * 3 + 1], sz = subp[m * 3 + 2];
  // gather x1 rows; store u32-pair transposed: ft2[c2][k]
#pragma unroll
  for (int i = 0; i < 16; ++i) {
    const int k = 2 * i + (lane >> 5);
    const int n = idxs[wid][k];
    ft2[wid][l31][k] = *(const uint_t*)(x1 + (long)n * HID + l31 * 2);
  }
  // A fragment: w^T[p][k], p = lane&15, k = 8*(lane>>4)+j  (computed in-lane)
  const int p = r16;
  const float kx = kpp[p][0], ky = kpp[p][1], kz = kpp[p][2];
  bf8_t afrag;
#pragma unroll
  for (int j = 0; j < 8; ++j) {
    const int k = g * 8 + j;
    const float dx = pts[wid][k][0] - sx - kx;
    const float dy = pts[wid][k][1] - sy - ky;
    const float dz = pts[wid][k][2] - sz - kz;
    const float dist = sqrtf(dx * dx + dy * dy + dz * dz);
    float w = fmaxf(0.f, 1.f - dist * 20.f);
    if (p == 15) w = 0.f;  // padding row
    afrag[j] = (short)f2bf(w);
  }
  // B fragments (apply BN1 + lrelu on the fly) + MFMA
  f4_t acc[4];
#pragma unroll
  for (int ni = 0; ni < 4; ++ni) acc[ni] = zero4();
#pragma unroll
  for (int ni = 0; ni < 4; ++ni) {
    const int c = r16 + ni * 16;
    const int c2 = c >> 1;
    const int sh = (c & 1) * 16;
    const float A = a1s[c], S = s1s[c];
    const uint_t* src = &ft2[wid][c2][g * 8];
    const u4_t v0 = *(const u4_t*)src;
    const u4_t v1 = *(const u4_t*)(src + 4);
    bf8_t bfrag;
#pragma unroll
    for (int j = 0; j < 4; ++j) {
      const float xa = __uint_as_float(((v0[j] >> sh) & 0xffffu) << 16);
      bfrag[j] = (short)f2bf(lrelu(A * xa + S));
      const float xb = __uint_as_float(((v1[j] >> sh) & 0xffffu) << 16);
      bfrag[4 + j] = (short)f2bf(lrelu(A * xb + S));
    }
    acc[ni] = __builtin_amdgcn_mfma_f32_16x16x32_bf16(afrag, bfrag, acc[ni], 0, 0, 0);
  }
  // store agg[m][p*64+c]  (D layout: row p = 4*g+rr, col c = r16+16*ni)
#pragma unroll
  for (int rr = 0; rr < 4; ++rr) {
    const int pp = g * 4 + rr;
    if (pp < PK) {
#pragma unroll
      for (int ni = 0; ni < 4; ++ni)
        agg[(long)m * QD + pp * HID + r16 + ni * 16] = f2bf(acc[ni][rr]);
    }
  }
  // shortcut: max over neighbors of features (bf16; max commutes with RNE)
  float mx0 = -3.0e38f, mx1 = -3.0e38f;
#pragma unroll
  for (int k = 0; k < KNBR; ++k) {
    const int n = idxs[wid][k];
    const ushort_t* fr = feat16 + (long)n * INDIM;
    mx0 = fmaxf(mx0, bf2f(fr[lane]));
    mx1 = fmaxf(mx1, bf2f(fr[lane + 64]));
  }
  scmax[(long)m * INDIM + lane] = (ushort_t)(__float_as_uint(mx0) >> 16);
  scmax[(long)m * INDIM + lane + 64] = (ushort_t)(__float_as_uint(mx1) >> 16);
}

// ---------------- kpconv GEMM: [M,960] @ [960,64] + lrelu -> x2 ----------------
__global__ __launch_bounds__(256) void kpgemm_kernel(const ushort_t* __restrict__ agg,
                                                     const ushort_t* __restrict__ kpwT,
                                                     ushort_t* __restrict__ x2) {
  const int tid = threadIdx.x, wid = tid >> 6, lane = tid & 63;
  const int g = lane >> 4, r16 = lane & 15;
  const int rowbase = blockIdx.x * 128 + wid * 32;
  f4_t acc[2][4];
#pragma unroll
  for (int mi = 0; mi < 2; ++mi)
#pragma unroll
    for (int ni = 0; ni < 4; ++ni) acc[mi][ni] = zero4();
  for (int kc = 0; kc < 30; ++kc) {
    const int k0 = kc * 32 + g * 8;
    bf8_t a[2], b[4];
#pragma unroll
    for (int mi = 0; mi < 2; ++mi) {
      int row = rowbase + mi * 16 + r16;
      if (row >= MSUB) row = 0;
      a[mi] = *(const bf8_t*)(agg + (long)row * QD + k0);
    }
#pragma unroll
    for (int ni = 0; ni < 4; ++ni)
      b[ni] = *(const bf8_t*)(kpwT + (r16 + ni * 16) * QD + k0);
#pragma unroll
    for (int mi = 0; mi < 2; ++mi)
#pragma unroll
      for (int ni = 0; ni < 4; ++ni)
        acc[mi][ni] = __builtin_amdgcn_mfma_f32_16x16x32_bf16(a[mi], b[ni], acc[mi][ni], 0, 0, 0);
  }
#pragma unroll
  for (int mi = 0; mi < 2; ++mi)
#pragma unroll
    for (int rr = 0; rr < 4; ++rr) {
      const int row = rowbase + mi * 16 + g * 4 + rr;
      if (row < MSUB) {
#pragma unroll
        for (int ni = 0; ni < 4; ++ni)
          x2[(long)row * HID + r16 + ni * 16] = f2bf(lrelu(acc[mi][ni][rr]));
      }
    }
}

// ---------------- conv2 / shortcut conv: [M,KD] @ [KD,256] + stats ----------------
template <int KD>
__global__ __launch_bounds__(256) void convT_kernel(const ushort_t* __restrict__ A,
                                                    const ushort_t* __restrict__ Bt,
                                                    ushort_t* __restrict__ Oraw,
                                                    float* __restrict__ ssum,
                                                    float* __restrict__ ssq) {
  const int tid = threadIdx.x, wid = tid >> 6, lane = tid & 63;
  const int g = lane >> 4, r16 = lane & 15;
  const int rowbase = blockIdx.x * 32;
  const int colbase = wid * 64;
  f4_t acc[2][4];
#pragma unroll
  for (int mi = 0; mi < 2; ++mi)
#pragma unroll
    for (int ni = 0; ni < 4; ++ni) acc[mi][ni] = zero4();
#pragma unroll
  for (int kc = 0; kc < KD / 32; ++kc) {
    const int k0 = kc * 32 + g * 8;
    bf8_t a[2], b[4];
#pragma unroll
    for (int mi = 0; mi < 2; ++mi) {
      int row = rowbase + mi * 16 + r16;
      if (row >= MSUB) row = 0;
      a[mi] = *(const bf8_t*)(A + (long)row * KD + k0);
    }
#pragma unroll
    for (int ni = 0; ni < 4; ++ni)
      b[ni] = *(const bf8_t*)(Bt + (long)(colbase + r16 + ni * 16) * KD + k0);
#pragma unroll
    for (int mi = 0; mi < 2; ++mi)
#pragma unroll
      for (int ni = 0; ni < 4; ++ni)
        acc[mi][ni] = __builtin_amdgcn_mfma_f32_16x16x32_bf16(a[mi], b[ni], acc[mi][ni], 0, 0, 0);
  }
  __shared__ float red[2][256];
  red[0][tid] = 0.f;
  red[1][tid] = 0.f;
  __syncthreads();
  float cs[4] = {0.f, 0.f, 0.f, 0.f}, cq[4] = {0.f, 0.f, 0.f, 0.f};
#pragma unroll
  for (int mi = 0; mi < 2; ++mi)
#pragma unroll
    for (int rr = 0; rr < 4; ++rr) {
      const int row = rowbase + mi * 16 + g * 4 + rr;
      if (row < MSUB) {
#pragma unroll
        for (int ni = 0; ni < 4; ++ni) {
          const float v = acc[mi][ni][rr];
          cs[ni] += v;
          cq[ni] += v * v;
          Oraw[(long)row * OUTDIM + colbase + r16 + ni * 16] = f2bf(v);
        }
      }
    }
#pragma unroll
  for (int ni = 0; ni < 4; ++ni) {
    atomicAdd(&red[0][colbase + r16 + ni * 16], cs[ni]);
    atomicAdd(&red[1][colbase + r16 + ni * 16], cq[ni]);
  }
  __syncthreads();
  atomicAdd(&ssum[tid], red[0][tid]);
  atomicAdd(&ssq[tid], red[1][tid]);
}

// ---------------- final: BN2/BN3 + lrelu + add + lrelu ----------------
__global__ __launch_bounds__(256) void final_kernel(const ushort_t* __restrict__ x3,
                                                    const ushort_t* __restrict__ sc,
                                                    const float* __restrict__ st,
                                                    float* __restrict__ out) {
  const int i = blockIdx.x * 256 + threadIdx.x;  // one group of 4 elems
  const int c0 = (i * 4) & 255;
  const uint2 xv = ((const uint2*)x3)[i];
  const uint2 sv = ((const uint2*)sc)[i];
  float xs[4] = {bf2f((ushort_t)(xv.x & 0xffffu)), bf2f((ushort_t)(xv.x >> 16)),
                 bf2f((ushort_t)(xv.y & 0xffffu)), bf2f((ushort_t)(xv.y >> 16))};
  float ss[4] = {bf2f((ushort_t)(sv.x & 0xffffu)), bf2f((ushort_t)(sv.x >> 16)),
                 bf2f((ushort_t)(sv.y & 0xffffu)), bf2f((ushort_t)(sv.y >> 16))};
  float r[4];
#pragma unroll
  for (int j = 0; j < 4; ++j) {
    const int c = c0 + j;
    const float v = lrelu(st[768 + c] * xs[j] + st[1024 + c]);
    const float u = lrelu(st[1792 + c] * ss[j] + st[2048 + c]);
    r[j] = lrelu(v + u);
  }
  ((float4*)out)[i] = make_float4(r[0], r[1], r[2], r[3]);
}

extern "C" void kernel_launch(void* const* d_in, const int* in_sizes, int n_in,
                              void* d_out, int out_size, void* d_ws, size_t ws_size,
                              hipStream_t stream) {
  (void)in_sizes; (void)n_in; (void)out_size;
  const float* points = (const float*)d_in[0];
  const float* subp = (const float*)d_in[1];
  const float* feat = (const float*)d_in[2];
  const int* pools = (const int*)d_in[3];
  const float* kp = (const float*)d_in[4];
  const float* W1 = (const float*)d_in[5];
  const float* g1 = (const float*)d_in[7];
  const float* be1 = (const float*)d_in[8];
  const float* kpw = (const float*)d_in[9];
  const float* W2 = (const float*)d_in[10];
  const float* g2 = (const float*)d_in[12];
  const float* be2 = (const float*)d_in[13];
  const float* Wsm = (const float*)d_in[14];
  const float* gs = (const float*)d_in[16];
  const float* bes = (const float*)d_in[17];
  float* out = (float*)d_out;

  char* w = (char*)d_ws;
  size_t o = 0;
  ushort_t* feat16 = (ushort_t*)(w + o); o += (size_t)NPTS * INDIM * 2;   // 51.2 MB
  ushort_t* x1 = (ushort_t*)(w + o);     o += (size_t)NPTS * HID * 2;     // 25.6 MB
  const size_t aggoff = o;
  ushort_t* agg = (ushort_t*)(w + o);    o += (size_t)MSUB * QD * 2;      // 96 MB
  ushort_t* scmax = (ushort_t*)(w + o);  o += (size_t)MSUB * INDIM * 2;   // 12.8 MB
  ushort_t* x2 = (ushort_t*)(w + o);     o += (size_t)MSUB * HID * 2;     // 6.4 MB
  ushort_t* W1t = (ushort_t*)(w + o);    o += HID * INDIM * 2;
  ushort_t* W2t = (ushort_t*)(w + o);    o += OUTDIM * HID * 2;
  ushort_t* Wst = (ushort_t*)(w + o);    o += OUTDIM * INDIM * 2;
  ushort_t* kpwT = (ushort_t*)(w + o);   o += HID * QD * 2;
  float* st = (float*)(w + o);           o += 2304 * 4;
  // overlay (agg dead after kpgemm):
  ushort_t* x3 = (ushort_t*)((char*)d_ws + aggoff);
  ushort_t* scraw = (ushort_t*)((char*)d_ws + aggoff + (size_t)MSUB * OUTDIM * 2);
  if (ws_size < o) return;  // ws too small: fail cleanly (output stays zero)

  hipMemsetAsync(st, 0, 2304 * 4, stream);
  prep_feat_kernel<<<NPTS * INDIM / 1024, 256, 0, stream>>>(feat, feat16);
  prep_w_kernel<<<64, 256, 0, stream>>>(W1, W2, Wsm, kpw, W1t, W2t, Wst, kpwT);
  conv1_kernel<<<(NPTS + 127) / 128, 256, 0, stream>>>(feat16, W1t, x1, st, st + 64);
  fin1_kernel<<<1, 64, 0, stream>>>(st, g1, be1);
  gather_kernel<<<MSUB / 4, 256, 0, stream>>>(points, subp, pools, kp, x1, feat16,
                                              st + 128, st + 192, agg, scmax);
  kpgemm_kernel<<<(MSUB + 127) / 128, 256, 0, stream>>>(agg, kpwT, x2);
  convT_kernel<HID><<<(MSUB + 31) / 32, 256, 0, stream>>>(x2, W2t, x3, st + 256, st + 512);
  convT_kernel<INDIM><<<(MSUB + 31) / 32, 256, 0, stream>>>(scmax, Wst, scraw, st + 1280, st + 1536);
  fin23_kernel<<<1, 256, 0, stream>>>(st, g2, be2, gs, bes);
  final_kernel<<<MSUB * OUTDIM / 1024, 256, 0, stream>>>(x3, scraw, st, out);
}